// Round 10
// baseline (202.611 us; speedup 1.0000x reference)
//
#include <hip/hip_runtime.h>
#include <cmath>

#define NN 4096
#define BB 4
#define CCH 8

// ---- workspace float offsets
#define OFF_W3JVAL 0         // 2670 (pad 2688)
#define OFF_W3JOUT 2688      // 10648 -> 13336 (pad 13440)
#define OFF_CTX0   13568     // 4 partials x 4*4096*96 floats -> ends 6305024 fl
#define CTXS       1572864
// ---- byte offsets, 16B aligned (after ctx: 6305024*4 = 25220096)
#define OFFB_KGH   25220096ULL   // u16[4*4096*32] = 1048576 B
#define OFFB_KGL   26268672ULL
#define OFFB_VG    27317248ULL   // u16[4*64*96*64] fp16 = 3145728 B
#define OFFB_WBH   30462976ULL   // u16[96*160] = 30720 B
#define OFFB_WBL   30493696ULL   // end 30524416

typedef short s16x8 __attribute__((ext_vector_type(8)));
typedef _Float16 f16x8 __attribute__((ext_vector_type(8)));
typedef float f32x4 __attribute__((ext_vector_type(4)));
typedef unsigned int u32x4 __attribute__((ext_vector_type(4)));
typedef unsigned int u32x2 __attribute__((ext_vector_type(2)));

static __device__ __forceinline__ unsigned short f2bf(float x){
  unsigned u = __float_as_uint(x);
  return (unsigned short)((u + 0x7FFFu + ((u >> 16) & 1u)) >> 16);
}
static __device__ __forceinline__ float bf2f(unsigned short h){
  return __uint_as_float(((unsigned)h) << 16);
}
static __device__ __forceinline__ unsigned pk2r(float v){
  unsigned short h = f2bf(v);
  unsigned short l = f2bf(v - bf2f(h));
  return ((unsigned)l << 16) | (unsigned)h;
}
static __device__ __forceinline__ unsigned short f2h(float x){
  return __builtin_bit_cast(unsigned short, (_Float16)x);
}
static __device__ __forceinline__ void unpk(u32x4 a, u32x4 b, s16x8& h, s16x8& l){
  u32x4 hw = { __builtin_amdgcn_perm(a[1],a[0],0x05040100u),
               __builtin_amdgcn_perm(a[3],a[2],0x05040100u),
               __builtin_amdgcn_perm(b[1],b[0],0x05040100u),
               __builtin_amdgcn_perm(b[3],b[2],0x05040100u)};
  u32x4 lw = { __builtin_amdgcn_perm(a[1],a[0],0x07060302u),
               __builtin_amdgcn_perm(a[3],a[2],0x07060302u),
               __builtin_amdgcn_perm(b[1],b[0],0x07060302u),
               __builtin_amdgcn_perm(b[3],b[2],0x07060302u)};
  h = __builtin_bit_cast(s16x8, hw);
  l = __builtin_bit_cast(s16x8, lw);
}

// ---------------------------------------------------------------- k_tab
// Wigner-3j builder, grid 14 x 512.
static __device__ __forceinline__ void qentf(int l, int r, int c, float& re, float& im){
  re=0.f; im=0.f;
  float s = ((l&3)==2)? -1.f : 1.f;
  const float rs2 = 0.70710678118654752440f;
  if(r < l){
    if(c == 2*l - r) re = s*rs2;
    else if(c == r)  im = -s*rs2;
  } else if(r == l){
    if(c == l) re = s;
  } else {
    float sg = ((r-l)&1)? -1.f : 1.f;
    if(c == r) re = s*sg*rs2;
    else if(c == 2*l - r) im = s*sg*rs2;
  }
}
__global__ __launch_bounds__(512) void k_tab(float* __restrict__ Wv, float* __restrict__ Wo){
  __shared__ float Ccf[2197];
  __shared__ float red[512];
  __shared__ double factS[20];
  int t = threadIdx.x;
  int p = blockIdx.x;
  if(t==0){
    double f=1.0; factS[0]=1.0;
    for(int i=1;i<20;i++){ f*=(double)i; factS[i]=f; }
  }
  const int L1[14]={4,4,6,4,6,6, 4,4,6,6,4,4,6,6};
  const int L2[14]={0,2,2,2,0,2, 4,6,4,6,4,6,4,6};
  const int L3[14]={4,4,4,6,6,6, 4,4,4,4,6,6,6,6};
  const int OFF[14]={0,81,486,1071,1656,1825, 0,729,1782,2835,4356,5409,6930,8451};
  int l1=L1[p], l2=L2[p], l3=L3[p];
  int d1=2*l1+1, d2=2*l2+1, d3=2*l3+1;
  int tot = d1*d2*d3;
  float* dst = (p<6) ? (Wv+OFF[p]) : (Wo+OFF[p]);
  float scale = (p<6) ? sqrtf((2.f*l3+1.f)/24.f) : sqrtf((2.f*l3+1.f)/256.f);
  __syncthreads();
  #pragma unroll 1
  for(int e=t; e<tot; e+=512){
    int i = e/(d2*d3), rem = e - i*(d2*d3), j = rem/d3, k = rem - j*d3;
    int m1=i-l1, m2=j-l2, m3=k-l3;
    double v=0.0;
    if(m1+m2==m3){
      double pref = sqrt((2.0*l3+1.0)*factS[l3+l1-l2]*factS[l3-l1+l2]*factS[l1+l2-l3]/factS[l1+l2+l3+1]);
      pref *= sqrt(factS[l3+m3]*factS[l3-m3]*factS[l1-m1]*factS[l1+m1]*factS[l2-m2]*factS[l2+m2]);
      double s=0.0;
      #pragma unroll 1
      for(int kk=0; kk<=l1+l2-l3; kk++){
        int dd0=kk, dd1=l1+l2-l3-kk, dd2=l1-m1-kk, dd3=l2+m2-kk, dd4=l3-l2+m1+kk, dd5=l3-l1-m2+kk;
        int mn=dd0;
        if(dd1<mn)mn=dd1; if(dd2<mn)mn=dd2; if(dd3<mn)mn=dd3; if(dd4<mn)mn=dd4; if(dd5<mn)mn=dd5;
        if(mn<0) continue;
        double prod = factS[dd0]*factS[dd1]*factS[dd2]*factS[dd3]*factS[dd4]*factS[dd5];
        s += ((kk&1)? -1.0:1.0)/prod;
      }
      v = pref*s;
    }
    Ccf[e]=(float)v;
  }
  __syncthreads();
  float nacc=0.f;
  #pragma unroll 1
  for(int e=t; e<tot; e+=512){
    int j = e/(d2*d3), rem = e - j*(d2*d3), l = rem/d3, n = rem - l*d3;
    float re = 0.f;
    #pragma unroll
    for(int ii=0; ii<2; ii++){
      int i = ii ? (2*l1 - j) : j;
      float q1r,q1i; qentf(l1,i,j,q1r,q1i);
      if(ii && i==j){ q1r=0.f; q1i=0.f; }
      #pragma unroll
      for(int kk=0; kk<2; kk++){
        int k = kk ? (2*l2 - l) : l;
        float q2r,q2i; qentf(l2,k,l,q2r,q2i);
        if(kk && k==l){ q2r=0.f; q2i=0.f; }
        float ar = q1r*q2r - q1i*q2i;
        float ai = q1r*q2i + q1i*q2r;
        #pragma unroll
        for(int mm=0; mm<2; mm++){
          int m = mm ? (2*l3 - n) : n;
          float q3r,q3i; qentf(l3,m,n,q3r,q3i);
          if(mm && m==n){ q3r=0.f; q3i=0.f; }
          float coef = ar*q3r + ai*q3i;
          re = fmaf(coef, Ccf[(i*d2+k)*d3+m], re);
        }
      }
    }
    dst[e]=re;
    nacc = fmaf(re,re,nacc);
  }
  red[t]=nacc;
  __syncthreads();
  #pragma unroll 1
  for(int s=256;s>0;s>>=1){
    if(t<s) red[t]+=red[t+s];
    __syncthreads();
  }
  float c = scale/sqrtf(red[0]);
  #pragma unroll 1
  for(int e=t; e<tot; e+=512) dst[e]*=c;
}

// ---------------------------------------------------------------- k_weights
__global__ void k_weights(const float* __restrict__ wli, const float* __restrict__ wval,
                          const float* __restrict__ wout, const float* __restrict__ wlo,
                          const float* __restrict__ Wv,
                          unsigned short* __restrict__ WBH, unsigned short* __restrict__ WBL){
  __shared__ float bws[48];
  __shared__ float scs[64];
  __shared__ float As[24];
  int t = threadIdx.x;
  if(t<48){
    const int val_l1[6]={0,0,1,0,1,1};
    int p=t>>3, w=t&7;
    float s=0.f;
    for(int u=0;u<8;u++) s = fmaf(wli[val_l1[p]*8+u], wval[(p*8+u)*8+w], s);
    bws[t]=s;
  }
  {
    const int out_l1[8]={0,0,1,1,0,0,1,1};
    const int out_l3[8]={0,0,0,0,1,1,1,1};
    int p=t>>3, v=t&7;
    float s=0.f;
    for(int u=0;u<8;u++){
      float a=wli[out_l1[p]*8+u];
      for(int w=0;w<8;w++) s = fmaf(wout[((p*8+u)*8+v)*8+w]*a, wlo[out_l3[p]*8+w], s);
    }
    scs[t]=s*0.35355339059327373f;
  }
  __syncthreads();
  if(t<24){
    int p=t/3, i3=t-3*p;
    int vp = (p&1)*3 + i3;
    float s=0.f;
    for(int w=0;w<8;w++) s = fmaf(scs[p*8+w], bws[vp*8+w], s);
    As[t]=s;
  }
  __syncthreads();
  int base = blockIdx.x*960;
  for(int k=0;k<15;k++){
    int cell = base + k*64 + t;
    int f = cell/160, c = cell - f*160;
    float v = 0.f;
    if(f < 88 && c < 132){
      int seg = f/22, off = f - seg*22;
      int even = (off < 9);
      int p = 2*seg + (even?0:1);
      int jo = even ? off : off-9;
      int l1, i, jj;
      if(c < 54){ l1=4; i=c/6; jj=c-6*i; }
      else { int cc=c-54; l1=6; i=cc/6; jj=cc-6*i; }
      if(even){
        if(l1==4 && jj==0)      v = As[p*3+0]*Wv[i*9+jo];
        else if(l1==4)          v = As[p*3+1]*Wv[81+(i*5+jj-1)*9+jo];
        else if(jj>=1)          v = As[p*3+2]*Wv[486+(i*5+jj-1)*9+jo];
      } else {
        if(l1==4 && jj>=1)      v = As[p*3+0]*Wv[1071+(i*5+jj-1)*13+jo];
        else if(l1==6 && jj==0) v = As[p*3+1]*Wv[1656+i*13+jo];
        else if(l1==6)          v = As[p*3+2]*Wv[1825+(i*5+jj-1)*13+jo];
      }
    } else if(f==88 && c==132){
      v = 1.0f;
    }
    unsigned short h = f2bf(v);
    WBH[cell] = h;
    WBL[cell] = f2bf(v - bf2f(h));
  }
}

// ---------------------------------------------------------------- k_prep (MFMA)
// grid 1024 x 128 (2 waves): block = (panel, m-tile) -> 16 points.
// R10: feat/sh loads vectorized to float2 (G13; 88B rows are 8B-aligned).
__launch_bounds__(128)
__global__ void k_prep(const float* __restrict__ feat, const float* __restrict__ sh,
                       const float* __restrict__ log_s, const float* __restrict__ pos_w,
                       const float* __restrict__ pos_b,
                       const unsigned short* __restrict__ WBH,
                       const unsigned short* __restrict__ WBL,
                       unsigned short* __restrict__ Kgh, unsigned short* __restrict__ Kgl,
                       unsigned short* __restrict__ Vg){
  __shared__ __align__(16) unsigned int Pbuf[16*164];
  __shared__ unsigned int Po[96*17];
  __shared__ float epbs[16];
  int tid = threadIdx.x;
  int w2 = tid >> 6, lane = tid & 63;
  int lm = lane & 15, quad = lane >> 4;
  int seg = w2*4 + quad;
  int panel = blockIdx.x >> 2, mt = blockIdx.x & 3;
  int idxp = panel*64 + mt*16 + lm;
  int n = idxp & (NN-1);
  const float* fp = feat + (size_t)idxp*22;
  const float* shp = sh + n*6;
  float f[22];
  #pragma unroll
  for(int c=0;c<11;c++){
    float2 v = *(const float2*)(fp + 2*c);
    f[2*c] = v.x; f[2*c+1] = v.y;
  }
  float y[6];
  #pragma unroll
  for(int j=0;j<3;j++){
    float2 v = *(const float2*)(shp + 2*j);
    y[2*j] = v.x; y[2*j+1] = v.y;
  }
  if(tid<16){
    float pb = pos_b[0];
    #pragma unroll
    for(int j=0;j<6;j++) pb = fmaf(y[j], pos_w[j], pb);
    epbs[lm] = __expf(pb);
    float n4=0.f, n6=0.f;
    #pragma unroll
    for(int c=0;c<9;c++) n4 += f[c]*f[c];
    #pragma unroll
    for(int c=9;c<22;c++) n6 += f[c]*f[c];
    n4 = fmaxf(sqrtf(n4), 1e-12f);
    n6 = fmaxf(sqrtf(n6), 1e-12f);
    float s4 = __expf(log_s[0]), s6 = __expf(log_s[1]);
    float a4 = sqrtf(s4)/n4, a6 = sqrtf(s6)/n6;
    unsigned short* kph = Kgh + (size_t)idxp*32;
    unsigned short* kpl = Kgl + (size_t)idxp*32;
    #pragma unroll
    for(int c=0;c<22;c++){
      float qv = f[c] * (c<9 ? a4 : a6);
      unsigned short h = f2bf(qv);
      kph[c]=h; kpl[c]=f2bf(qv - bf2f(h));
    }
    #pragma unroll
    for(int c=22;c<32;c++){ kph[c]=0; kpl[c]=0; }
  }
  #pragma unroll
  for(int j4=0;j4<5;j4++){
    u32x4 wv;
    #pragma unroll
    for(int e=0;e<4;e++){
      int c = seg*20 + j4*4 + e;
      float pv;
      if(c<54){ int i=c/6, jj=c-6*i; pv = f[i]*y[jj]; }
      else if(c<132){ int cc=c-54; int i=cc/6, jj=cc-6*i; pv = f[9+i]*y[jj]; }
      else if(c==132) pv = 1.0f;
      else pv = 0.0f;
      wv[e] = pk2r(pv);
    }
    *(u32x4*)&Pbuf[lm*164 + seg*20 + j4*4] = wv;
  }
  __syncthreads();
  f32x4 acc[3];
  #pragma unroll
  for(int ft=0;ft<3;ft++)
    #pragma unroll
    for(int i=0;i<4;i++) acc[ft][i]=0.f;
  for(int kc=0;kc<5;kc++){
    const u32x4* ap = (const u32x4*)&Pbuf[lm*164 + kc*32 + quad*8];
    s16x8 Ah, Al;
    unpk(ap[0], ap[1], Ah, Al);
    #pragma unroll
    for(int ft=0;ft<3;ft++){
      int ftg = w2*3 + ft;
      size_t bo = (size_t)(ftg*16+lm)*160 + kc*32 + quad*8;
      s16x8 Bh = *(const s16x8*)(WBH + bo);
      s16x8 Bl = *(const s16x8*)(WBL + bo);
      f32x4 a = acc[ft];
      a = __builtin_amdgcn_mfma_f32_16x16x32_bf16(Al, Bl, a, 0,0,0);
      a = __builtin_amdgcn_mfma_f32_16x16x32_bf16(Al, Bh, a, 0,0,0);
      a = __builtin_amdgcn_mfma_f32_16x16x32_bf16(Ah, Bl, a, 0,0,0);
      a = __builtin_amdgcn_mfma_f32_16x16x32_bf16(Ah, Bh, a, 0,0,0);
      acc[ft] = a;
    }
  }
  #pragma unroll
  for(int r=0;r<4;r++){
    float e = epbs[quad*4 + r];
    #pragma unroll
    for(int ft=0;ft<3;ft++){
      int ftg = w2*3 + ft;
      Po[(ftg*16+lm)*17 + quad*4 + r] = (unsigned)f2h(acc[ft][r]*e);
    }
  }
  __syncthreads();
  unsigned int* vO32 = (unsigned int*)(Vg + (size_t)panel*96*64);
  #pragma unroll
  for(int wv=0; wv<6; wv++){
    int idx2 = wv*128 + tid;
    int g = idx2 >> 3, j = idx2 & 7;
    unsigned lo = Po[g*17 + 2*j] & 0xFFFFu;
    unsigned hi = Po[g*17 + 2*j + 1] & 0xFFFFu;
    vO32[g*32 + mt*8 + j] = lo | (hi<<16);
  }
}

// ---------------------------------------------------------------- k_attn
// R10: V DIRECT FROM GLOBAL (register operand), K-only LDS double buffer.
// Evidence: three k_attn restructures (R7/R8/R9) were total-neutral; per-CU
// accounting says the binding pipe is LDS (~2160 cyc/panel/CU), and ~100 of
// the 180 ops are V reads that all 8 waves DUPLICATE (identical 12KB panel).
// The V fragment each lane needs is a contiguous global run by k_prep's
// construction: VB + panel*6144 + (ft*16+lm)*64 + c*32 + quad*8  (u16) --
// verified identical to unswizzling the old staging path. So V moves to
// global->register loads (12 dwordx4/wave/panel, L2-resident, counted-vmcnt
// cover under the S phase, no barrier coupling). LDS keeps only permuted K
// (2 x 8KB dbuf): LDS ops/panel/CU 180 -> ~72. V loads are consumed before
// the per-panel __syncthreads -> its vmcnt drain is free.
// Structure else = R8: 32 q-rows/wave, bpermute-free key permutation,
// grid 256 = 4b x 4kh x 16qb, 1 block/CU, waves_per_eu(2,2).
#define LDSK  0
#define LDSKL 4096
#define KBUF  8192
__global__ __launch_bounds__(512)
__attribute__((amdgpu_waves_per_eu(2, 2)))
void k_attn(const unsigned short* __restrict__ Kgh,
            const unsigned short* __restrict__ Kgl,
            const unsigned short* __restrict__ Vg,
            float* __restrict__ ctx0){
  __shared__ __align__(16) unsigned char lds[2*KBUF];   // 16384 B
  int tid = threadIdx.x;
  int lane = tid & 63, w = tid >> 6;
  int lm = lane & 15, quad = lane >> 4;
  int blk = blockIdx.x;
  int b = blk & 3, kh = (blk>>2)&3, qb = blk >> 4;   // qb 0..15
  const unsigned short* KhB = Kgh + (size_t)b*NN*32;
  const unsigned short* KlB = Kgl + (size_t)b*NN*32;
  const unsigned short* VB  = Vg  + (size_t)b*64*96*64;
  float* ctx = ctx0 + (size_t)kh*CTXS + (size_t)b*NN*96;

  // Q fragments: two q-tiles per wave (B-operand: col=lm, k=quad*8+j)
  s16x8 qh[2], ql[2];
  #pragma unroll
  for(int q2=0;q2<2;q2++){
    size_t ro = (size_t)(qb*256 + w*32 + q2*16 + lm)*32 + (size_t)quad*8;
    qh[q2] = *(const s16x8*)(KhB + ro);
    ql[q2] = *(const s16x8*)(KlB + ro);
  }

  // loop-invariant offsets
  int kro = lm*64 + ((quad ^ ((lm>>1)&3))<<4);     // K LDS read: tile row lm, col quad
  int vbase = lm*128 + quad*16;                    // V global per-lane byte base

  // K staging: 512 granules (16B) over 512 threads, 1/thread.
  // Source rows PERMUTED: LDS (t, rr) holds actual key
  //   kact = 32*(t&1) + 8*(rr>>2) + 4*(t>>1) + (rr&3)
  int dofs, sofs; bool isH;
  {
    int g2 = tid & 255;
    int row = g2>>2, col = g2&3;          // row = t*16+rr in 0..63
    int t = row>>4, rr = row&15;
    int kact = 32*(t&1) + 8*(rr>>2) + 4*(t>>1) + (rr&3);
    isH = (tid < 256);
    sofs = kact*64 + col*16;
    dofs = (isH ? LDSK : LDSKL) + row*64 + ((col ^ ((row>>1)&3))<<4);
  }

  f32x4 acc[2][6];
  #pragma unroll
  for(int q2=0;q2<2;q2++)
    #pragma unroll
    for(int ft=0;ft<6;ft++)
      #pragma unroll
      for(int i=0;i<4;i++) acc[2==2?q2:0][ft][i]=0.f;

  unsigned Wt[2][4][2];   // [q2][kt][word]
  f16x8 vv[2][6];         // V fragments for current panel (registers)
  u32x4 stg0;

#define MFB(A,Bv,C) __builtin_amdgcn_mfma_f32_16x16x32_bf16(A,Bv,C,0,0,0)
#define MFH(A,Bv,C) __builtin_amdgcn_mfma_f32_16x16x32_f16(A,Bv,C,0,0,0)

#define STG_ISSUE(T) { \
  const unsigned short* kp_ = (isH ? KhB : KlB) + (size_t)(kh*16+(T))*2048; \
  stg0 = *(const u32x4*)((const char*)kp_ + sofs); }

#define STG_WRITE(BN) { *(u32x4*)&lds[(BN)*KBUF + dofs] = stg0; }

#define VLOAD(T) { \
  const char* vb_ = (const char*)(VB + (size_t)(kh*16+(T))*6144) + vbase; \
  _Pragma("unroll") \
  for(int c=0;c<2;c++) \
  _Pragma("unroll") \
  for(int ft=0;ft<6;ft++) \
    vv[c][ft] = *(const f16x8*)(vb_ + ft*2048 + c*64); }

#define SPH(B) { \
  _Pragma("unroll") \
  for(int kt=0;kt<4;kt++){ \
    s16x8 kfh = *(const s16x8*)&lds[(B)*KBUF + LDSK  + kt*1024 + kro]; \
    s16x8 kfl = *(const s16x8*)&lds[(B)*KBUF + LDSKL + kt*1024 + kro]; \
    _Pragma("unroll") \
    for(int q2=0;q2<2;q2++){ \
      f32x4 s_ = {0.f,0.f,0.f,0.f}; \
      s_ = MFB(kfl, qh[q2], s_); \
      s_ = MFB(kfh, ql[q2], s_); \
      s_ = MFB(kfh, qh[q2], s_); \
      Wt[q2][kt][0] = (unsigned)f2h(__expf(s_[0])) | ((unsigned)f2h(__expf(s_[1]))<<16); \
      Wt[q2][kt][1] = (unsigned)f2h(__expf(s_[2])) | ((unsigned)f2h(__expf(s_[3]))<<16); \
    } \
  } }

#define PVH() { \
  _Pragma("unroll") \
  for(int c=0;c<2;c++){ \
    u32x4 paw0 = {Wt[0][c][0], Wt[0][c][1], Wt[0][c+2][0], Wt[0][c+2][1]}; \
    u32x4 paw1 = {Wt[1][c][0], Wt[1][c][1], Wt[1][c+2][0], Wt[1][c+2][1]}; \
    f16x8 PA0 = __builtin_bit_cast(f16x8, paw0); \
    f16x8 PA1 = __builtin_bit_cast(f16x8, paw1); \
    _Pragma("unroll") \
    for(int ft=0;ft<6;ft++){ \
      acc[0][ft] = MFH(PA0, vv[c][ft], acc[0][ft]); \
      acc[1][ft] = MFH(PA1, vv[c][ft], acc[1][ft]); } \
  } }

  // ---- prologue: stage K panel 0 into buf 0
  STG_ISSUE(0);
  STG_WRITE(0);
  __syncthreads();

  // ---- main: 2x-unrolled for static buffer indices; one barrier per panel.
  // Body t: issue K(t+1) -> V(t) global loads -> S(t) [K LDS] -> PV(t)
  // [V regs, vmcnt-covered by S] -> write K(t+1) -> barrier.
  #pragma unroll 1
  for(int tp=0; tp<8; tp++){
    int t0 = 2*tp;
    STG_ISSUE(t0+1);          // always valid (t0+1 <= 15)
    VLOAD(t0);
    SPH(0);
    PVH();
    STG_WRITE(1);
    __syncthreads();
    if(t0+2 < 16){ STG_ISSUE(t0+2); }
    VLOAD(t0+1);
    SPH(1);
    PVH();
    if(t0+2 < 16){ STG_WRITE(0); }
    __syncthreads();
  }

#undef MFB
#undef MFH
#undef STG_ISSUE
#undef STG_WRITE
#undef VLOAD
#undef SPH
#undef PVH

  // ---- epilogue: ctx store (D-layout: col=lm per ft, row=quad*4+r)
  #pragma unroll
  for(int q2=0;q2<2;q2++){
    #pragma unroll
    for(int ft=0;ft<6;ft++){
      int col = ft*16 + lm;
      #pragma unroll
      for(int r=0;r<4;r++){
        int row = qb*256 + w*32 + q2*16 + quad*4 + r;
        ctx[(size_t)row*96 + col] = acc[q2][ft][r];
      }
    }
  }
}

// ---------------------------------------------------------------- k_out
// R7 config kept: 16 points/block, grid 2048, (256,4) -> no spills,
// 8 blocks/CU via 17.9KB LDS + 64-VGPR occupancy step.
__launch_bounds__(256, 4)
__global__ void k_out(const float* __restrict__ feat, const float* __restrict__ ctxA,
                      const float* __restrict__ w3jout, float* __restrict__ out){
  __shared__ float gbuf[16*45];
  __shared__ float fbuf[16*24];
  __shared__ float dls[4*64*13];
  __shared__ float inv[16];
  int tid = threadIdx.x;
  int typ = blockIdx.x & 1;
  int n0 = (blockIdx.x>>1)*16;
  int gc0 = typ*44;
  for(int i=tid;i<16*44;i+=256){
    int pt=i/44, c=i-pt*44;
    const float* base = ctxA + (size_t)(n0+pt)*96 + gc0 + c;
    gbuf[pt*45+c] = base[0]+base[CTXS]+base[2*CTXS]+base[3*CTXS];
  }
  for(int i=tid;i<16*22;i+=256){
    int pt=i/22, c=i-pt*22;
    fbuf[pt*24+c] = feat[(size_t)(n0+pt)*22+c];
  }
  if(tid<16){
    const float* bd = ctxA + (size_t)(n0+tid)*96 + 88;
    inv[tid] = 1.0f/(bd[0]+bd[CTXS]+bd[2*CTXS]+bd[3*CTXS]);
  }
  __syncthreads();
  int lane = tid&63, w = tid>>6;
  int pt = lane&15, sub = lane>>4;
  float fR[13], gR[13], d[13];
  {
    int FB = (w&2)?9:0;
    int fn = (w&2)?13:9;
    #pragma unroll 13
    for(int i=0;i<13;i++) fR[i] = (i<fn) ? fbuf[pt*24 + FB + i] : 0.f;
    int GBl = (w==0)?0:(w==1)?9:(w==2)?22:31;
    int jn = (w&1)?13:9;
    #pragma unroll 13
    for(int j=0;j<13;j++) gR[j] = (j<jn) ? gbuf[pt*45 + GBl + j] : 0.f;
  }
  #pragma unroll 13
  for(int k=0;k<13;k++) d[k]=0.f;

  // i-loop strided across sub: i = sub + 4*ii (ii count compile-time)
#define PATHR(ID,JD,KD,WO) \
  _Pragma("unroll") \
  for(int ii=0;ii<((ID)+3)/4;ii++){ int i=sub+4*ii; if(i<(ID)){ float fv=fR[i]; \
    _Pragma("unroll") \
    for(int j=0;j<(JD);j++){ float val=fv*gR[j]; \
      const float* wp = w3jout + (WO) + (i*(JD)+j)*(KD); \
      _Pragma("unroll") \
      for(int k=0;k<(KD);k++) d[k] = fmaf(val, wp[k], d[k]); } } }

  int pcase = typ*4 + w;
  switch(pcase){
    case 0: PATHR(9,9,9, 0)       break;
    case 1: PATHR(9,13,9, 729)    break;
    case 2: PATHR(13,9,9, 1782)   break;
    case 3: PATHR(13,13,9, 2835)  break;
    case 4: PATHR(9,9,13, 4356)   break;
    case 5: PATHR(9,13,13, 5409)  break;
    case 6: PATHR(13,9,13, 6930)  break;
    default:PATHR(13,13,13, 8451) break;
  }
#undef PATHR
  {
    float* dp = &dls[(w*64+lane)*13];
    #pragma unroll 13
    for(int k=0;k<13;k++) dp[k]=d[k];
  }
  __syncthreads();
  {
    int KD = typ?13:9;
    int kb = typ?9:0;
    int pt2 = tid&15, kc = tid>>4;   // kc 0..15
    if(kc < KD){
      float s = 0.f;
      #pragma unroll
      for(int ww=0;ww<4;ww++)
        #pragma unroll
        for(int ss=0;ss<4;ss++)
          s += dls[(ww*64 + ss*16 + pt2)*13 + kc];
      out[(size_t)(n0+pt2)*22 + kb + kc] = s*inv[pt2];
    }
  }
}

// ---------------------------------------------------------------- launch
extern "C" void kernel_launch(void* const* d_in, const int* in_sizes, int n_in,
                              void* d_out, int out_size, void* d_ws, size_t ws_size,
                              hipStream_t stream){
  (void)in_sizes; (void)n_in; (void)out_size; (void)ws_size;
  const float* feat =(const float*)d_in[0];
  const float* sh   =(const float*)d_in[1];
  const float* log_s=(const float*)d_in[2];
  const float* pos_w=(const float*)d_in[3];
  const float* pos_b=(const float*)d_in[4];
  const float* wli  =(const float*)d_in[5];
  const float* wval =(const float*)d_in[6];
  const float* wout =(const float*)d_in[7];
  const float* wlo  =(const float*)d_in[8];
  float* outp=(float*)d_out;
  float* wsf=(float*)d_ws;

  unsigned short* Kgh=(unsigned short*)((char*)d_ws + OFFB_KGH);
  unsigned short* Kgl=(unsigned short*)((char*)d_ws + OFFB_KGL);
  unsigned short* Vg =(unsigned short*)((char*)d_ws + OFFB_VG);
  unsigned short* WBH=(unsigned short*)((char*)d_ws + OFFB_WBH);
  unsigned short* WBL=(unsigned short*)((char*)d_ws + OFFB_WBL);

  hipLaunchKernelGGL(k_tab, dim3(14), dim3(512), 0, stream,
                     wsf+OFF_W3JVAL, wsf+OFF_W3JOUT);
  hipLaunchKernelGGL(k_weights, dim3(16), dim3(64), 0, stream,
                     wli, wval, wout, wlo, wsf+OFF_W3JVAL, WBH, WBL);
  hipLaunchKernelGGL(k_prep, dim3(1024), dim3(128), 0, stream,
                     feat, sh, log_s, pos_w, pos_b, WBH, WBL,
                     Kgh, Kgl, Vg);
  hipLaunchKernelGGL(k_attn, dim3(256), dim3(512), 0, stream,
                     Kgh, Kgl, Vg, wsf+OFF_CTX0);
  hipLaunchKernelGGL(k_out, dim3(2048), dim3(256), 0, stream,
                     feat, wsf+OFF_CTX0, wsf+OFF_W3JOUT, outp);
}

// Round 11
// 202.144 us; speedup vs baseline: 1.0023x; 1.0023x over previous
//
#include <hip/hip_runtime.h>
#include <cmath>

#define NN 4096
#define BB 4
#define CCH 8

// ---- workspace float offsets
#define OFF_W3JVAL 0         // 2670 (pad 2688)
#define OFF_W3JOUT 2688      // 10648 -> 13336 (pad 13440)
#define OFF_CTX0   13568     // 4 partials x 4*4096*96 floats -> ends 6305024 fl
#define CTXS       1572864
// ---- byte offsets, 16B aligned (after ctx: 6305024*4 = 25220096)
#define OFFB_KGH   25220096ULL   // u16[4*4096*32] = 1048576 B
#define OFFB_KGL   26268672ULL
#define OFFB_VG    27317248ULL   // u16[4*64*96*64] fp16 = 3145728 B
#define OFFB_WBH   30462976ULL   // u16[96*160] = 30720 B
#define OFFB_WBL   30493696ULL   // end 30524416

typedef short s16x8 __attribute__((ext_vector_type(8)));
typedef _Float16 f16x8 __attribute__((ext_vector_type(8)));
typedef float f32x4 __attribute__((ext_vector_type(4)));
typedef unsigned int u32x4 __attribute__((ext_vector_type(4)));
typedef unsigned int u32x2 __attribute__((ext_vector_type(2)));

static __device__ __forceinline__ unsigned short f2bf(float x){
  unsigned u = __float_as_uint(x);
  return (unsigned short)((u + 0x7FFFu + ((u >> 16) & 1u)) >> 16);
}
static __device__ __forceinline__ float bf2f(unsigned short h){
  return __uint_as_float(((unsigned)h) << 16);
}
static __device__ __forceinline__ unsigned pk2r(float v){
  unsigned short h = f2bf(v);
  unsigned short l = f2bf(v - bf2f(h));
  return ((unsigned)l << 16) | (unsigned)h;
}
static __device__ __forceinline__ unsigned short f2h(float x){
  return __builtin_bit_cast(unsigned short, (_Float16)x);
}
static __device__ __forceinline__ void unpk(u32x4 a, u32x4 b, s16x8& h, s16x8& l){
  u32x4 hw = { __builtin_amdgcn_perm(a[1],a[0],0x05040100u),
               __builtin_amdgcn_perm(a[3],a[2],0x05040100u),
               __builtin_amdgcn_perm(b[1],b[0],0x05040100u),
               __builtin_amdgcn_perm(b[3],b[2],0x05040100u)};
  u32x4 lw = { __builtin_amdgcn_perm(a[1],a[0],0x07060302u),
               __builtin_amdgcn_perm(a[3],a[2],0x07060302u),
               __builtin_amdgcn_perm(b[1],b[0],0x07060302u),
               __builtin_amdgcn_perm(b[3],b[2],0x07060302u)};
  h = __builtin_bit_cast(s16x8, hw);
  l = __builtin_bit_cast(s16x8, lw);
}
// LDS-only barrier: drains lgkm (ds ops) but leaves global loads (vmcnt)
// in flight across the barrier -- required for the cross-body V prefetch.
// Memory clobbers pin ds ops on both sides (m201 pattern, used R0-R3).
static __device__ __forceinline__ void barrier_lds(){
  __asm__ volatile("s_waitcnt lgkmcnt(0)" ::: "memory");
  __builtin_amdgcn_s_barrier();
  __asm__ volatile("" ::: "memory");
}

// ---------------------------------------------------------------- k_tab
// Wigner-3j builder, grid 14 x 512.
static __device__ __forceinline__ void qentf(int l, int r, int c, float& re, float& im){
  re=0.f; im=0.f;
  float s = ((l&3)==2)? -1.f : 1.f;
  const float rs2 = 0.70710678118654752440f;
  if(r < l){
    if(c == 2*l - r) re = s*rs2;
    else if(c == r)  im = -s*rs2;
  } else if(r == l){
    if(c == l) re = s;
  } else {
    float sg = ((r-l)&1)? -1.f : 1.f;
    if(c == r) re = s*sg*rs2;
    else if(c == 2*l - r) im = s*sg*rs2;
  }
}
__global__ __launch_bounds__(512) void k_tab(float* __restrict__ Wv, float* __restrict__ Wo){
  __shared__ float Ccf[2197];
  __shared__ float red[512];
  __shared__ double factS[20];
  int t = threadIdx.x;
  int p = blockIdx.x;
  if(t==0){
    double f=1.0; factS[0]=1.0;
    for(int i=1;i<20;i++){ f*=(double)i; factS[i]=f; }
  }
  const int L1[14]={4,4,6,4,6,6, 4,4,6,6,4,4,6,6};
  const int L2[14]={0,2,2,2,0,2, 4,6,4,6,4,6,4,6};
  const int L3[14]={4,4,4,6,6,6, 4,4,4,4,6,6,6,6};
  const int OFF[14]={0,81,486,1071,1656,1825, 0,729,1782,2835,4356,5409,6930,8451};
  int l1=L1[p], l2=L2[p], l3=L3[p];
  int d1=2*l1+1, d2=2*l2+1, d3=2*l3+1;
  int tot = d1*d2*d3;
  float* dst = (p<6) ? (Wv+OFF[p]) : (Wo+OFF[p]);
  float scale = (p<6) ? sqrtf((2.f*l3+1.f)/24.f) : sqrtf((2.f*l3+1.f)/256.f);
  __syncthreads();
  #pragma unroll 1
  for(int e=t; e<tot; e+=512){
    int i = e/(d2*d3), rem = e - i*(d2*d3), j = rem/d3, k = rem - j*d3;
    int m1=i-l1, m2=j-l2, m3=k-l3;
    double v=0.0;
    if(m1+m2==m3){
      double pref = sqrt((2.0*l3+1.0)*factS[l3+l1-l2]*factS[l3-l1+l2]*factS[l1+l2-l3]/factS[l1+l2+l3+1]);
      pref *= sqrt(factS[l3+m3]*factS[l3-m3]*factS[l1-m1]*factS[l1+m1]*factS[l2-m2]*factS[l2+m2]);
      double s=0.0;
      #pragma unroll 1
      for(int kk=0; kk<=l1+l2-l3; kk++){
        int dd0=kk, dd1=l1+l2-l3-kk, dd2=l1-m1-kk, dd3=l2+m2-kk, dd4=l3-l2+m1+kk, dd5=l3-l1-m2+kk;
        int mn=dd0;
        if(dd1<mn)mn=dd1; if(dd2<mn)mn=dd2; if(dd3<mn)mn=dd3; if(dd4<mn)mn=dd4; if(dd5<mn)mn=dd5;
        if(mn<0) continue;
        double prod = factS[dd0]*factS[dd1]*factS[dd2]*factS[dd3]*factS[dd4]*factS[dd5];
        s += ((kk&1)? -1.0:1.0)/prod;
      }
      v = pref*s;
    }
    Ccf[e]=(float)v;
  }
  __syncthreads();
  float nacc=0.f;
  #pragma unroll 1
  for(int e=t; e<tot; e+=512){
    int j = e/(d2*d3), rem = e - j*(d2*d3), l = rem/d3, n = rem - l*d3;
    float re = 0.f;
    #pragma unroll
    for(int ii=0; ii<2; ii++){
      int i = ii ? (2*l1 - j) : j;
      float q1r,q1i; qentf(l1,i,j,q1r,q1i);
      if(ii && i==j){ q1r=0.f; q1i=0.f; }
      #pragma unroll
      for(int kk=0; kk<2; kk++){
        int k = kk ? (2*l2 - l) : l;
        float q2r,q2i; qentf(l2,k,l,q2r,q2i);
        if(kk && k==l){ q2r=0.f; q2i=0.f; }
        float ar = q1r*q2r - q1i*q2i;
        float ai = q1r*q2i + q1i*q2r;
        #pragma unroll
        for(int mm=0; mm<2; mm++){
          int m = mm ? (2*l3 - n) : n;
          float q3r,q3i; qentf(l3,m,n,q3r,q3i);
          if(mm && m==n){ q3r=0.f; q3i=0.f; }
          float coef = ar*q3r + ai*q3i;
          re = fmaf(coef, Ccf[(i*d2+k)*d3+m], re);
        }
      }
    }
    dst[e]=re;
    nacc = fmaf(re,re,nacc);
  }
  red[t]=nacc;
  __syncthreads();
  #pragma unroll 1
  for(int s=256;s>0;s>>=1){
    if(t<s) red[t]+=red[t+s];
    __syncthreads();
  }
  float c = scale/sqrtf(red[0]);
  #pragma unroll 1
  for(int e=t; e<tot; e+=512) dst[e]*=c;
}

// ---------------------------------------------------------------- k_weights
__global__ void k_weights(const float* __restrict__ wli, const float* __restrict__ wval,
                          const float* __restrict__ wout, const float* __restrict__ wlo,
                          const float* __restrict__ Wv,
                          unsigned short* __restrict__ WBH, unsigned short* __restrict__ WBL){
  __shared__ float bws[48];
  __shared__ float scs[64];
  __shared__ float As[24];
  int t = threadIdx.x;
  if(t<48){
    const int val_l1[6]={0,0,1,0,1,1};
    int p=t>>3, w=t&7;
    float s=0.f;
    for(int u=0;u<8;u++) s = fmaf(wli[val_l1[p]*8+u], wval[(p*8+u)*8+w], s);
    bws[t]=s;
  }
  {
    const int out_l1[8]={0,0,1,1,0,0,1,1};
    const int out_l3[8]={0,0,0,0,1,1,1,1};
    int p=t>>3, v=t&7;
    float s=0.f;
    for(int u=0;u<8;u++){
      float a=wli[out_l1[p]*8+u];
      for(int w=0;w<8;w++) s = fmaf(wout[((p*8+u)*8+v)*8+w]*a, wlo[out_l3[p]*8+w], s);
    }
    scs[t]=s*0.35355339059327373f;
  }
  __syncthreads();
  if(t<24){
    int p=t/3, i3=t-3*p;
    int vp = (p&1)*3 + i3;
    float s=0.f;
    for(int w=0;w<8;w++) s = fmaf(scs[p*8+w], bws[vp*8+w], s);
    As[t]=s;
  }
  __syncthreads();
  int base = blockIdx.x*960;
  for(int k=0;k<15;k++){
    int cell = base + k*64 + t;
    int f = cell/160, c = cell - f*160;
    float v = 0.f;
    if(f < 88 && c < 132){
      int seg = f/22, off = f - seg*22;
      int even = (off < 9);
      int p = 2*seg + (even?0:1);
      int jo = even ? off : off-9;
      int l1, i, jj;
      if(c < 54){ l1=4; i=c/6; jj=c-6*i; }
      else { int cc=c-54; l1=6; i=cc/6; jj=cc-6*i; }
      if(even){
        if(l1==4 && jj==0)      v = As[p*3+0]*Wv[i*9+jo];
        else if(l1==4)          v = As[p*3+1]*Wv[81+(i*5+jj-1)*9+jo];
        else if(jj>=1)          v = As[p*3+2]*Wv[486+(i*5+jj-1)*9+jo];
      } else {
        if(l1==4 && jj>=1)      v = As[p*3+0]*Wv[1071+(i*5+jj-1)*13+jo];
        else if(l1==6 && jj==0) v = As[p*3+1]*Wv[1656+i*13+jo];
        else if(l1==6)          v = As[p*3+2]*Wv[1825+(i*5+jj-1)*13+jo];
      }
    } else if(f==88 && c==132){
      v = 1.0f;
    }
    unsigned short h = f2bf(v);
    WBH[cell] = h;
    WBL[cell] = f2bf(v - bf2f(h));
  }
}

// ---------------------------------------------------------------- k_prep (MFMA)
// grid 1024 x 128 (2 waves): block = (panel, m-tile) -> 16 points.
// feat/sh loads vectorized to float2 (G13; 88B rows are 8B-aligned).
__launch_bounds__(128)
__global__ void k_prep(const float* __restrict__ feat, const float* __restrict__ sh,
                       const float* __restrict__ log_s, const float* __restrict__ pos_w,
                       const float* __restrict__ pos_b,
                       const unsigned short* __restrict__ WBH,
                       const unsigned short* __restrict__ WBL,
                       unsigned short* __restrict__ Kgh, unsigned short* __restrict__ Kgl,
                       unsigned short* __restrict__ Vg){
  __shared__ __align__(16) unsigned int Pbuf[16*164];
  __shared__ unsigned int Po[96*17];
  __shared__ float epbs[16];
  int tid = threadIdx.x;
  int w2 = tid >> 6, lane = tid & 63;
  int lm = lane & 15, quad = lane >> 4;
  int seg = w2*4 + quad;
  int panel = blockIdx.x >> 2, mt = blockIdx.x & 3;
  int idxp = panel*64 + mt*16 + lm;
  int n = idxp & (NN-1);
  const float* fp = feat + (size_t)idxp*22;
  const float* shp = sh + n*6;
  float f[22];
  #pragma unroll
  for(int c=0;c<11;c++){
    float2 v = *(const float2*)(fp + 2*c);
    f[2*c] = v.x; f[2*c+1] = v.y;
  }
  float y[6];
  #pragma unroll
  for(int j=0;j<3;j++){
    float2 v = *(const float2*)(shp + 2*j);
    y[2*j] = v.x; y[2*j+1] = v.y;
  }
  if(tid<16){
    float pb = pos_b[0];
    #pragma unroll
    for(int j=0;j<6;j++) pb = fmaf(y[j], pos_w[j], pb);
    epbs[lm] = __expf(pb);
    float n4=0.f, n6=0.f;
    #pragma unroll
    for(int c=0;c<9;c++) n4 += f[c]*f[c];
    #pragma unroll
    for(int c=9;c<22;c++) n6 += f[c]*f[c];
    n4 = fmaxf(sqrtf(n4), 1e-12f);
    n6 = fmaxf(sqrtf(n6), 1e-12f);
    float s4 = __expf(log_s[0]), s6 = __expf(log_s[1]);
    float a4 = sqrtf(s4)/n4, a6 = sqrtf(s6)/n6;
    unsigned short* kph = Kgh + (size_t)idxp*32;
    unsigned short* kpl = Kgl + (size_t)idxp*32;
    #pragma unroll
    for(int c=0;c<22;c++){
      float qv = f[c] * (c<9 ? a4 : a6);
      unsigned short h = f2bf(qv);
      kph[c]=h; kpl[c]=f2bf(qv - bf2f(h));
    }
    #pragma unroll
    for(int c=22;c<32;c++){ kph[c]=0; kpl[c]=0; }
  }
  #pragma unroll
  for(int j4=0;j4<5;j4++){
    u32x4 wv;
    #pragma unroll
    for(int e=0;e<4;e++){
      int c = seg*20 + j4*4 + e;
      float pv;
      if(c<54){ int i=c/6, jj=c-6*i; pv = f[i]*y[jj]; }
      else if(c<132){ int cc=c-54; int i=cc/6, jj=cc-6*i; pv = f[9+i]*y[jj]; }
      else if(c==132) pv = 1.0f;
      else pv = 0.0f;
      wv[e] = pk2r(pv);
    }
    *(u32x4*)&Pbuf[lm*164 + seg*20 + j4*4] = wv;
  }
  __syncthreads();
  f32x4 acc[3];
  #pragma unroll
  for(int ft=0;ft<3;ft++)
    #pragma unroll
    for(int i=0;i<4;i++) acc[ft][i]=0.f;
  for(int kc=0;kc<5;kc++){
    const u32x4* ap = (const u32x4*)&Pbuf[lm*164 + kc*32 + quad*8];
    s16x8 Ah, Al;
    unpk(ap[0], ap[1], Ah, Al);
    #pragma unroll
    for(int ft=0;ft<3;ft++){
      int ftg = w2*3 + ft;
      size_t bo = (size_t)(ftg*16+lm)*160 + kc*32 + quad*8;
      s16x8 Bh = *(const s16x8*)(WBH + bo);
      s16x8 Bl = *(const s16x8*)(WBL + bo);
      f32x4 a = acc[ft];
      a = __builtin_amdgcn_mfma_f32_16x16x32_bf16(Al, Bl, a, 0,0,0);
      a = __builtin_amdgcn_mfma_f32_16x16x32_bf16(Al, Bh, a, 0,0,0);
      a = __builtin_amdgcn_mfma_f32_16x16x32_bf16(Ah, Bl, a, 0,0,0);
      a = __builtin_amdgcn_mfma_f32_16x16x32_bf16(Ah, Bh, a, 0,0,0);
      acc[ft] = a;
    }
  }
  #pragma unroll
  for(int r=0;r<4;r++){
    float e = epbs[quad*4 + r];
    #pragma unroll
    for(int ft=0;ft<3;ft++){
      int ftg = w2*3 + ft;
      Po[(ftg*16+lm)*17 + quad*4 + r] = (unsigned)f2h(acc[ft][r]*e);
    }
  }
  __syncthreads();
  unsigned int* vO32 = (unsigned int*)(Vg + (size_t)panel*96*64);
  #pragma unroll
  for(int wv=0; wv<6; wv++){
    int idx2 = wv*128 + tid;
    int g = idx2 >> 3, j = idx2 & 7;
    unsigned lo = Po[g*17 + 2*j] & 0xFFFFu;
    unsigned hi = Po[g*17 + 2*j + 1] & 0xFFFFu;
    vO32[g*32 + mt*8 + j] = lo | (hi<<16);
  }
}

// ---------------------------------------------------------------- k_attn
// R11: R10 (V direct-from-global, K-only LDS dbuf) + V REGISTER DOUBLE
// BUFFER + lgkm-only barrier. R10 regressed (43.7->60.4us) because V was
// issued and consumed in the SAME body: at 2 waves/SIMD the S-phase alone
// couldn't cover the L2 tail, and __syncthreads' vmcnt(0) drain boxed each
// body in. Fix: body t issues V(t+1) into the other register bank and PV
// consumes V(t) loaded LAST body (full-body cover ~2000cy >> ~300cy L2);
// barrier_lds() (lgkmcnt-only + raw s_barrier) lets K+V global loads stay
// in flight across the barrier. Issue order K-then-V per body keeps the K
// load oldest, so the ds_write's counted vmcnt wait leaves V in flight.
// vv banks are named (vvA/vvB), all indices static (rule #20).
// Registers ~195 < 256 budget (waves_per_eu(2,2)); spill sentinel:
// WRITE_SIZE must stay 24576.
#define LDSK  0
#define LDSKL 4096
#define KBUF  8192
__global__ __launch_bounds__(512)
__attribute__((amdgpu_waves_per_eu(2, 2)))
void k_attn(const unsigned short* __restrict__ Kgh,
            const unsigned short* __restrict__ Kgl,
            const unsigned short* __restrict__ Vg,
            float* __restrict__ ctx0){
  __shared__ __align__(16) unsigned char lds[2*KBUF];   // 16384 B
  int tid = threadIdx.x;
  int lane = tid & 63, w = tid >> 6;
  int lm = lane & 15, quad = lane >> 4;
  int blk = blockIdx.x;
  int b = blk & 3, kh = (blk>>2)&3, qb = blk >> 4;   // qb 0..15
  const unsigned short* KhB = Kgh + (size_t)b*NN*32;
  const unsigned short* KlB = Kgl + (size_t)b*NN*32;
  const unsigned short* VB  = Vg  + (size_t)b*64*96*64;
  float* ctx = ctx0 + (size_t)kh*CTXS + (size_t)b*NN*96;

  // Q fragments: two q-tiles per wave (B-operand: col=lm, k=quad*8+j)
  s16x8 qh[2], ql[2];
  #pragma unroll
  for(int q2=0;q2<2;q2++){
    size_t ro = (size_t)(qb*256 + w*32 + q2*16 + lm)*32 + (size_t)quad*8;
    qh[q2] = *(const s16x8*)(KhB + ro);
    ql[q2] = *(const s16x8*)(KlB + ro);
  }

  // loop-invariant offsets
  int kro = lm*64 + ((quad ^ ((lm>>1)&3))<<4);     // K LDS read: tile row lm, col quad
  int vbase = lm*128 + quad*16;                    // V global per-lane byte base

  // K staging: 512 granules (16B) over 512 threads, 1/thread.
  // Source rows PERMUTED: LDS (t, rr) holds actual key
  //   kact = 32*(t&1) + 8*(rr>>2) + 4*(t>>1) + (rr&3)
  int dofs, sofs; bool isH;
  {
    int g2 = tid & 255;
    int row = g2>>2, col = g2&3;          // row = t*16+rr in 0..63
    int t = row>>4, rr = row&15;
    int kact = 32*(t&1) + 8*(rr>>2) + 4*(t>>1) + (rr&3);
    isH = (tid < 256);
    sofs = kact*64 + col*16;
    dofs = (isH ? LDSK : LDSKL) + row*64 + ((col ^ ((row>>1)&3))<<4);
  }

  f32x4 acc[2][6];
  #pragma unroll
  for(int q2=0;q2<2;q2++)
    #pragma unroll
    for(int ft=0;ft<6;ft++)
      #pragma unroll
      for(int i=0;i<4;i++) acc[q2][ft][i]=0.f;

  unsigned Wt[2][4][2];       // [q2][kt][word]
  f16x8 vvA[2][6], vvB[2][6]; // V register double-buffer (static banks)
  u32x4 stg0;

#define MFB(A,Bv,C) __builtin_amdgcn_mfma_f32_16x16x32_bf16(A,Bv,C,0,0,0)
#define MFH(A,Bv,C) __builtin_amdgcn_mfma_f32_16x16x32_f16(A,Bv,C,0,0,0)

#define STG_ISSUE(T) { \
  const unsigned short* kp_ = (isH ? KhB : KlB) + (size_t)(kh*16+(T))*2048; \
  stg0 = *(const u32x4*)((const char*)kp_ + sofs); }

#define STG_WRITE(BN) { *(u32x4*)&lds[(BN)*KBUF + dofs] = stg0; }

#define VLOAD(T,BANK) { \
  const char* vb_ = (const char*)(VB + (size_t)(kh*16+(T))*6144) + vbase; \
  _Pragma("unroll") \
  for(int c=0;c<2;c++) \
  _Pragma("unroll") \
  for(int ft=0;ft<6;ft++) \
    BANK[c][ft] = *(const f16x8*)(vb_ + ft*2048 + c*64); }

#define SPH(B) { \
  _Pragma("unroll") \
  for(int kt=0;kt<4;kt++){ \
    s16x8 kfh = *(const s16x8*)&lds[(B)*KBUF + LDSK  + kt*1024 + kro]; \
    s16x8 kfl = *(const s16x8*)&lds[(B)*KBUF + LDSKL + kt*1024 + kro]; \
    _Pragma("unroll") \
    for(int q2=0;q2<2;q2++){ \
      f32x4 s_ = {0.f,0.f,0.f,0.f}; \
      s_ = MFB(kfl, qh[q2], s_); \
      s_ = MFB(kfh, ql[q2], s_); \
      s_ = MFB(kfh, qh[q2], s_); \
      Wt[q2][kt][0] = (unsigned)f2h(__expf(s_[0])) | ((unsigned)f2h(__expf(s_[1]))<<16); \
      Wt[q2][kt][1] = (unsigned)f2h(__expf(s_[2])) | ((unsigned)f2h(__expf(s_[3]))<<16); \
    } \
  } }

#define PVH(BANK) { \
  _Pragma("unroll") \
  for(int c=0;c<2;c++){ \
    u32x4 paw0 = {Wt[0][c][0], Wt[0][c][1], Wt[0][c+2][0], Wt[0][c+2][1]}; \
    u32x4 paw1 = {Wt[1][c][0], Wt[1][c][1], Wt[1][c+2][0], Wt[1][c+2][1]}; \
    f16x8 PA0 = __builtin_bit_cast(f16x8, paw0); \
    f16x8 PA1 = __builtin_bit_cast(f16x8, paw1); \
    _Pragma("unroll") \
    for(int ft=0;ft<6;ft++){ \
      acc[0][ft] = MFH(PA0, BANK[c][ft], acc[0][ft]); \
      acc[1][ft] = MFH(PA1, BANK[c][ft], acc[1][ft]); } \
  } }

  // ---- prologue: K panel 0 -> LDS buf 0; V(0) -> bank A
  STG_ISSUE(0);
  STG_WRITE(0);
  VLOAD(0, vvA);
  __syncthreads();

  // ---- main: 2x-unrolled; one lgkm-only barrier per panel.
  // Body t: issue K(t+1), issue V(t+1) -> other bank, S(t) [K LDS],
  // PV(t) [V bank loaded LAST body], write K(t+1), barrier_lds.
  #pragma unroll 1
  for(int tp=0; tp<8; tp++){
    int t0 = 2*tp;
    // body t0 (even): V bank A current, prefetch into B
    STG_ISSUE(t0+1);          // always valid (t0+1 <= 15)
    VLOAD(t0+1, vvB);
    SPH(0);
    PVH(vvA);
    STG_WRITE(1);
    barrier_lds();
    // body t0+1 (odd): V bank B current, prefetch into A
    if(t0+2 < 16){ STG_ISSUE(t0+2); VLOAD(t0+2, vvA); }
    SPH(1);
    PVH(vvB);
    if(t0+2 < 16){ STG_WRITE(0); }
    barrier_lds();
  }

#undef MFB
#undef MFH
#undef STG_ISSUE
#undef STG_WRITE
#undef VLOAD
#undef SPH
#undef PVH

  // ---- epilogue: ctx store (D-layout: col=lm per ft, row=quad*4+r)
  #pragma unroll
  for(int q2=0;q2<2;q2++){
    #pragma unroll
    for(int ft=0;ft<6;ft++){
      int col = ft*16 + lm;
      #pragma unroll
      for(int r=0;r<4;r++){
        int row = qb*256 + w*32 + q2*16 + quad*4 + r;
        ctx[(size_t)row*96 + col] = acc[q2][ft][r];
      }
    }
  }
}

// ---------------------------------------------------------------- k_out
// R7 config kept: 16 points/block, grid 2048, (256,4) -> no spills,
// 8 blocks/CU via 17.9KB LDS + 64-VGPR occupancy step.
__launch_bounds__(256, 4)
__global__ void k_out(const float* __restrict__ feat, const float* __restrict__ ctxA,
                      const float* __restrict__ w3jout, float* __restrict__ out){
  __shared__ float gbuf[16*45];
  __shared__ float fbuf[16*24];
  __shared__ float dls[4*64*13];
  __shared__ float inv[16];
  int tid = threadIdx.x;
  int typ = blockIdx.x & 1;
  int n0 = (blockIdx.x>>1)*16;
  int gc0 = typ*44;
  for(int i=tid;i<16*44;i+=256){
    int pt=i/44, c=i-pt*44;
    const float* base = ctxA + (size_t)(n0+pt)*96 + gc0 + c;
    gbuf[pt*45+c] = base[0]+base[CTXS]+base[2*CTXS]+base[3*CTXS];
  }
  for(int i=tid;i<16*22;i+=256){
    int pt=i/22, c=i-pt*22;
    fbuf[pt*24+c] = feat[(size_t)(n0+pt)*22+c];
  }
  if(tid<16){
    const float* bd = ctxA + (size_t)(n0+tid)*96 + 88;
    inv[tid] = 1.0f/(bd[0]+bd[CTXS]+bd[2*CTXS]+bd[3*CTXS]);
  }
  __syncthreads();
  int lane = tid&63, w = tid>>6;
  int pt = lane&15, sub = lane>>4;
  float fR[13], gR[13], d[13];
  {
    int FB = (w&2)?9:0;
    int fn = (w&2)?13:9;
    #pragma unroll 13
    for(int i=0;i<13;i++) fR[i] = (i<fn) ? fbuf[pt*24 + FB + i] : 0.f;
    int GBl = (w==0)?0:(w==1)?9:(w==2)?22:31;
    int jn = (w&1)?13:9;
    #pragma unroll 13
    for(int j=0;j<13;j++) gR[j] = (j<jn) ? gbuf[pt*45 + GBl + j] : 0.f;
  }
  #pragma unroll 13
  for(int k=0;k<13;k++) d[k]=0.f;

  // i-loop strided across sub: i = sub + 4*ii (ii count compile-time)
#define PATHR(ID,JD,KD,WO) \
  _Pragma("unroll") \
  for(int ii=0;ii<((ID)+3)/4;ii++){ int i=sub+4*ii; if(i<(ID)){ float fv=fR[i]; \
    _Pragma("unroll") \
    for(int j=0;j<(JD);j++){ float val=fv*gR[j]; \
      const float* wp = w3jout + (WO) + (i*(JD)+j)*(KD); \
      _Pragma("unroll") \
      for(int k=0;k<(KD);k++) d[k] = fmaf(val, wp[k], d[k]); } } }

  int pcase = typ*4 + w;
  switch(pcase){
    case 0: PATHR(9,9,9, 0)       break;
    case 1: PATHR(9,13,9, 729)    break;
    case 2: PATHR(13,9,9, 1782)   break;
    case 3: PATHR(13,13,9, 2835)  break;
    case 4: PATHR(9,9,13, 4356)   break;
    case 5: PATHR(9,13,13, 5409)  break;
    case 6: PATHR(13,9,13, 6930)  break;
    default:PATHR(13,13,13, 8451) break;
  }
#undef PATHR
  {
    float* dp = &dls[(w*64+lane)*13];
    #pragma unroll 13
    for(int k=0;k<13;k++) dp[k]=d[k];
  }
  __syncthreads();
  {
    int KD = typ?13:9;
    int kb = typ?9:0;
    int pt2 = tid&15, kc = tid>>4;   // kc 0..15
    if(kc < KD){
      float s = 0.f;
      #pragma unroll
      for(int ww=0;ww<4;ww++)
        #pragma unroll
        for(int ss=0;ss<4;ss++)
          s += dls[(ww*64 + ss*16 + pt2)*13 + kc];
      out[(size_t)(n0+pt2)*22 + kb + kc] = s*inv[pt2];
    }
  }
}

// ---------------------------------------------------------------- launch
extern "C" void kernel_launch(void* const* d_in, const int* in_sizes, int n_in,
                              void* d_out, int out_size, void* d_ws, size_t ws_size,
                              hipStream_t stream){
  (void)in_sizes; (void)n_in; (void)out_size; (void)ws_size;
  const float* feat =(const float*)d_in[0];
  const float* sh   =(const float*)d_in[1];
  const float* log_s=(const float*)d_in[2];
  const float* pos_w=(const float*)d_in[3];
  const float* pos_b=(const float*)d_in[4];
  const float* wli  =(const float*)d_in[5];
  const float* wval =(const float*)d_in[6];
  const float* wout =(const float*)d_in[7];
  const float* wlo  =(const float*)d_in[8];
  float* outp=(float*)d_out;
  float* wsf=(float*)d_ws;

  unsigned short* Kgh=(unsigned short*)((char*)d_ws + OFFB_KGH);
  unsigned short* Kgl=(unsigned short*)((char*)d_ws + OFFB_KGL);
  unsigned short* Vg =(unsigned short*)((char*)d_ws + OFFB_VG);
  unsigned short* WBH=(unsigned short*)((char*)d_ws + OFFB_WBH);
  unsigned short* WBL=(unsigned short*)((char*)d_ws + OFFB_WBL);

  hipLaunchKernelGGL(k_tab, dim3(14), dim3(512), 0, stream,
                     wsf+OFF_W3JVAL, wsf+OFF_W3JOUT);
  hipLaunchKernelGGL(k_weights, dim3(16), dim3(64), 0, stream,
                     wli, wval, wout, wlo, wsf+OFF_W3JVAL, WBH, WBL);
  hipLaunchKernelGGL(k_prep, dim3(1024), dim3(128), 0, stream,
                     feat, sh, log_s, pos_w, pos_b, WBH, WBL,
                     Kgh, Kgl, Vg);
  hipLaunchKernelGGL(k_attn, dim3(256), dim3(512), 0, stream,
                     Kgh, Kgl, Vg, wsf+OFF_CTX0);
  hipLaunchKernelGGL(k_out, dim3(2048), dim3(256), 0, stream,
                     feat, wsf+OFF_CTX0, wsf+OFF_W3JOUT, outp);
}

// Round 12
// 175.707 us; speedup vs baseline: 1.1531x; 1.1505x over previous
//
#include <hip/hip_runtime.h>
#include <cmath>

#define NN 4096
#define BB 4
#define CCH 8

// ---- workspace float offsets
#define OFF_W3JVAL 0         // 2670 (pad 2688)
#define OFF_W3JOUT 2688      // 10648 -> 13336 (pad 13440)
#define OFF_CTX0   13568     // 4 partials x 4*4096*96 floats -> ends 6305024 fl
#define CTXS       1572864
// ---- byte offsets, 16B aligned (after ctx: 6305024*4 = 25220096)
#define OFFB_KGH   25220096ULL   // u16[4*4096*32] = 1048576 B
#define OFFB_KGL   26268672ULL
#define OFFB_VG    27317248ULL   // u16[4*64*96*64] fp16 = 3145728 B
#define OFFB_WBH   30462976ULL   // u16[96*160] = 30720 B
#define OFFB_WBL   30493696ULL   // end 30524416

typedef short s16x8 __attribute__((ext_vector_type(8)));
typedef _Float16 f16x8 __attribute__((ext_vector_type(8)));
typedef float f32x4 __attribute__((ext_vector_type(4)));
typedef unsigned int u32x4 __attribute__((ext_vector_type(4)));
typedef unsigned int u32x2 __attribute__((ext_vector_type(2)));

static __device__ __forceinline__ unsigned short f2bf(float x){
  unsigned u = __float_as_uint(x);
  return (unsigned short)((u + 0x7FFFu + ((u >> 16) & 1u)) >> 16);
}
static __device__ __forceinline__ float bf2f(unsigned short h){
  return __uint_as_float(((unsigned)h) << 16);
}
static __device__ __forceinline__ unsigned pk2r(float v){
  unsigned short h = f2bf(v);
  unsigned short l = f2bf(v - bf2f(h));
  return ((unsigned)l << 16) | (unsigned)h;
}
static __device__ __forceinline__ unsigned short f2h(float x){
  return __builtin_bit_cast(unsigned short, (_Float16)x);
}
static __device__ __forceinline__ void unpk(u32x4 a, u32x4 b, s16x8& h, s16x8& l){
  u32x4 hw = { __builtin_amdgcn_perm(a[1],a[0],0x05040100u),
               __builtin_amdgcn_perm(a[3],a[2],0x05040100u),
               __builtin_amdgcn_perm(b[1],b[0],0x05040100u),
               __builtin_amdgcn_perm(b[3],b[2],0x05040100u)};
  u32x4 lw = { __builtin_amdgcn_perm(a[1],a[0],0x07060302u),
               __builtin_amdgcn_perm(a[3],a[2],0x07060302u),
               __builtin_amdgcn_perm(b[1],b[0],0x07060302u),
               __builtin_amdgcn_perm(b[3],b[2],0x07060302u)};
  h = __builtin_bit_cast(s16x8, hw);
  l = __builtin_bit_cast(s16x8, lw);
}

// ---------------------------------------------------------------- k_tab
// Wigner-3j builder, grid 14 x 512.
static __device__ __forceinline__ void qentf(int l, int r, int c, float& re, float& im){
  re=0.f; im=0.f;
  float s = ((l&3)==2)? -1.f : 1.f;
  const float rs2 = 0.70710678118654752440f;
  if(r < l){
    if(c == 2*l - r) re = s*rs2;
    else if(c == r)  im = -s*rs2;
  } else if(r == l){
    if(c == l) re = s;
  } else {
    float sg = ((r-l)&1)? -1.f : 1.f;
    if(c == r) re = s*sg*rs2;
    else if(c == 2*l - r) im = s*sg*rs2;
  }
}
__global__ __launch_bounds__(512) void k_tab(float* __restrict__ Wv, float* __restrict__ Wo){
  __shared__ float Ccf[2197];
  __shared__ float red[512];
  __shared__ double factS[20];
  int t = threadIdx.x;
  int p = blockIdx.x;
  if(t==0){
    double f=1.0; factS[0]=1.0;
    for(int i=1;i<20;i++){ f*=(double)i; factS[i]=f; }
  }
  const int L1[14]={4,4,6,4,6,6, 4,4,6,6,4,4,6,6};
  const int L2[14]={0,2,2,2,0,2, 4,6,4,6,4,6,4,6};
  const int L3[14]={4,4,4,6,6,6, 4,4,4,4,6,6,6,6};
  const int OFF[14]={0,81,486,1071,1656,1825, 0,729,1782,2835,4356,5409,6930,8451};
  int l1=L1[p], l2=L2[p], l3=L3[p];
  int d1=2*l1+1, d2=2*l2+1, d3=2*l3+1;
  int tot = d1*d2*d3;
  float* dst = (p<6) ? (Wv+OFF[p]) : (Wo+OFF[p]);
  float scale = (p<6) ? sqrtf((2.f*l3+1.f)/24.f) : sqrtf((2.f*l3+1.f)/256.f);
  __syncthreads();
  #pragma unroll 1
  for(int e=t; e<tot; e+=512){
    int i = e/(d2*d3), rem = e - i*(d2*d3), j = rem/d3, k = rem - j*d3;
    int m1=i-l1, m2=j-l2, m3=k-l3;
    double v=0.0;
    if(m1+m2==m3){
      double pref = sqrt((2.0*l3+1.0)*factS[l3+l1-l2]*factS[l3-l1+l2]*factS[l1+l2-l3]/factS[l1+l2+l3+1]);
      pref *= sqrt(factS[l3+m3]*factS[l3-m3]*factS[l1-m1]*factS[l1+m1]*factS[l2-m2]*factS[l2+m2]);
      double s=0.0;
      #pragma unroll 1
      for(int kk=0; kk<=l1+l2-l3; kk++){
        int dd0=kk, dd1=l1+l2-l3-kk, dd2=l1-m1-kk, dd3=l2+m2-kk, dd4=l3-l2+m1+kk, dd5=l3-l1-m2+kk;
        int mn=dd0;
        if(dd1<mn)mn=dd1; if(dd2<mn)mn=dd2; if(dd3<mn)mn=dd3; if(dd4<mn)mn=dd4; if(dd5<mn)mn=dd5;
        if(mn<0) continue;
        double prod = factS[dd0]*factS[dd1]*factS[dd2]*factS[dd3]*factS[dd4]*factS[dd5];
        s += ((kk&1)? -1.0:1.0)/prod;
      }
      v = pref*s;
    }
    Ccf[e]=(float)v;
  }
  __syncthreads();
  float nacc=0.f;
  #pragma unroll 1
  for(int e=t; e<tot; e+=512){
    int j = e/(d2*d3), rem = e - j*(d2*d3), l = rem/d3, n = rem - l*d3;
    float re = 0.f;
    #pragma unroll
    for(int ii=0; ii<2; ii++){
      int i = ii ? (2*l1 - j) : j;
      float q1r,q1i; qentf(l1,i,j,q1r,q1i);
      if(ii && i==j){ q1r=0.f; q1i=0.f; }
      #pragma unroll
      for(int kk=0; kk<2; kk++){
        int k = kk ? (2*l2 - l) : l;
        float q2r,q2i; qentf(l2,k,l,q2r,q2i);
        if(kk && k==l){ q2r=0.f; q2i=0.f; }
        float ar = q1r*q2r - q1i*q2i;
        float ai = q1r*q2i + q1i*q2r;
        #pragma unroll
        for(int mm=0; mm<2; mm++){
          int m = mm ? (2*l3 - n) : n;
          float q3r,q3i; qentf(l3,m,n,q3r,q3i);
          if(mm && m==n){ q3r=0.f; q3i=0.f; }
          float coef = ar*q3r + ai*q3i;
          re = fmaf(coef, Ccf[(i*d2+k)*d3+m], re);
        }
      }
    }
    dst[e]=re;
    nacc = fmaf(re,re,nacc);
  }
  red[t]=nacc;
  __syncthreads();
  #pragma unroll 1
  for(int s=256;s>0;s>>=1){
    if(t<s) red[t]+=red[t+s];
    __syncthreads();
  }
  float c = scale/sqrtf(red[0]);
  #pragma unroll 1
  for(int e=t; e<tot; e+=512) dst[e]*=c;
}

// ---------------------------------------------------------------- k_weights
__global__ void k_weights(const float* __restrict__ wli, const float* __restrict__ wval,
                          const float* __restrict__ wout, const float* __restrict__ wlo,
                          const float* __restrict__ Wv,
                          unsigned short* __restrict__ WBH, unsigned short* __restrict__ WBL){
  __shared__ float bws[48];
  __shared__ float scs[64];
  __shared__ float As[24];
  int t = threadIdx.x;
  if(t<48){
    const int val_l1[6]={0,0,1,0,1,1};
    int p=t>>3, w=t&7;
    float s=0.f;
    for(int u=0;u<8;u++) s = fmaf(wli[val_l1[p]*8+u], wval[(p*8+u)*8+w], s);
    bws[t]=s;
  }
  {
    const int out_l1[8]={0,0,1,1,0,0,1,1};
    const int out_l3[8]={0,0,0,0,1,1,1,1};
    int p=t>>3, v=t&7;
    float s=0.f;
    for(int u=0;u<8;u++){
      float a=wli[out_l1[p]*8+u];
      for(int w=0;w<8;w++) s = fmaf(wout[((p*8+u)*8+v)*8+w]*a, wlo[out_l3[p]*8+w], s);
    }
    scs[t]=s*0.35355339059327373f;
  }
  __syncthreads();
  if(t<24){
    int p=t/3, i3=t-3*p;
    int vp = (p&1)*3 + i3;
    float s=0.f;
    for(int w=0;w<8;w++) s = fmaf(scs[p*8+w], bws[vp*8+w], s);
    As[t]=s;
  }
  __syncthreads();
  int base = blockIdx.x*960;
  for(int k=0;k<15;k++){
    int cell = base + k*64 + t;
    int f = cell/160, c = cell - f*160;
    float v = 0.f;
    if(f < 88 && c < 132){
      int seg = f/22, off = f - seg*22;
      int even = (off < 9);
      int p = 2*seg + (even?0:1);
      int jo = even ? off : off-9;
      int l1, i, jj;
      if(c < 54){ l1=4; i=c/6; jj=c-6*i; }
      else { int cc=c-54; l1=6; i=cc/6; jj=cc-6*i; }
      if(even){
        if(l1==4 && jj==0)      v = As[p*3+0]*Wv[i*9+jo];
        else if(l1==4)          v = As[p*3+1]*Wv[81+(i*5+jj-1)*9+jo];
        else if(jj>=1)          v = As[p*3+2]*Wv[486+(i*5+jj-1)*9+jo];
      } else {
        if(l1==4 && jj>=1)      v = As[p*3+0]*Wv[1071+(i*5+jj-1)*13+jo];
        else if(l1==6 && jj==0) v = As[p*3+1]*Wv[1656+i*13+jo];
        else if(l1==6)          v = As[p*3+2]*Wv[1825+(i*5+jj-1)*13+jo];
      }
    } else if(f==88 && c==132){
      v = 1.0f;
    }
    unsigned short h = f2bf(v);
    WBH[cell] = h;
    WBL[cell] = f2bf(v - bf2f(h));
  }
}

// ---------------------------------------------------------------- k_prep (MFMA)
// grid 1024 x 128 (2 waves): block = (panel, m-tile) -> 16 points.
// feat/sh loads vectorized to float2 (G13; 88B rows are 8B-aligned).
__launch_bounds__(128)
__global__ void k_prep(const float* __restrict__ feat, const float* __restrict__ sh,
                       const float* __restrict__ log_s, const float* __restrict__ pos_w,
                       const float* __restrict__ pos_b,
                       const unsigned short* __restrict__ WBH,
                       const unsigned short* __restrict__ WBL,
                       unsigned short* __restrict__ Kgh, unsigned short* __restrict__ Kgl,
                       unsigned short* __restrict__ Vg){
  __shared__ __align__(16) unsigned int Pbuf[16*164];
  __shared__ unsigned int Po[96*17];
  __shared__ float epbs[16];
  int tid = threadIdx.x;
  int w2 = tid >> 6, lane = tid & 63;
  int lm = lane & 15, quad = lane >> 4;
  int seg = w2*4 + quad;
  int panel = blockIdx.x >> 2, mt = blockIdx.x & 3;
  int idxp = panel*64 + mt*16 + lm;
  int n = idxp & (NN-1);
  const float* fp = feat + (size_t)idxp*22;
  const float* shp = sh + n*6;
  float f[22];
  #pragma unroll
  for(int c=0;c<11;c++){
    float2 v = *(const float2*)(fp + 2*c);
    f[2*c] = v.x; f[2*c+1] = v.y;
  }
  float y[6];
  #pragma unroll
  for(int j=0;j<3;j++){
    float2 v = *(const float2*)(shp + 2*j);
    y[2*j] = v.x; y[2*j+1] = v.y;
  }
  if(tid<16){
    float pb = pos_b[0];
    #pragma unroll
    for(int j=0;j<6;j++) pb = fmaf(y[j], pos_w[j], pb);
    epbs[lm] = __expf(pb);
    float n4=0.f, n6=0.f;
    #pragma unroll
    for(int c=0;c<9;c++) n4 += f[c]*f[c];
    #pragma unroll
    for(int c=9;c<22;c++) n6 += f[c]*f[c];
    n4 = fmaxf(sqrtf(n4), 1e-12f);
    n6 = fmaxf(sqrtf(n6), 1e-12f);
    float s4 = __expf(log_s[0]), s6 = __expf(log_s[1]);
    float a4 = sqrtf(s4)/n4, a6 = sqrtf(s6)/n6;
    unsigned short* kph = Kgh + (size_t)idxp*32;
    unsigned short* kpl = Kgl + (size_t)idxp*32;
    #pragma unroll
    for(int c=0;c<22;c++){
      float qv = f[c] * (c<9 ? a4 : a6);
      unsigned short h = f2bf(qv);
      kph[c]=h; kpl[c]=f2bf(qv - bf2f(h));
    }
    #pragma unroll
    for(int c=22;c<32;c++){ kph[c]=0; kpl[c]=0; }
  }
  #pragma unroll
  for(int j4=0;j4<5;j4++){
    u32x4 wv;
    #pragma unroll
    for(int e=0;e<4;e++){
      int c = seg*20 + j4*4 + e;
      float pv;
      if(c<54){ int i=c/6, jj=c-6*i; pv = f[i]*y[jj]; }
      else if(c<132){ int cc=c-54; int i=cc/6, jj=cc-6*i; pv = f[9+i]*y[jj]; }
      else if(c==132) pv = 1.0f;
      else pv = 0.0f;
      wv[e] = pk2r(pv);
    }
    *(u32x4*)&Pbuf[lm*164 + seg*20 + j4*4] = wv;
  }
  __syncthreads();
  f32x4 acc[3];
  #pragma unroll
  for(int ft=0;ft<3;ft++)
    #pragma unroll
    for(int i=0;i<4;i++) acc[ft][i]=0.f;
  for(int kc=0;kc<5;kc++){
    const u32x4* ap = (const u32x4*)&Pbuf[lm*164 + kc*32 + quad*8];
    s16x8 Ah, Al;
    unpk(ap[0], ap[1], Ah, Al);
    #pragma unroll
    for(int ft=0;ft<3;ft++){
      int ftg = w2*3 + ft;
      size_t bo = (size_t)(ftg*16+lm)*160 + kc*32 + quad*8;
      s16x8 Bh = *(const s16x8*)(WBH + bo);
      s16x8 Bl = *(const s16x8*)(WBL + bo);
      f32x4 a = acc[ft];
      a = __builtin_amdgcn_mfma_f32_16x16x32_bf16(Al, Bl, a, 0,0,0);
      a = __builtin_amdgcn_mfma_f32_16x16x32_bf16(Al, Bh, a, 0,0,0);
      a = __builtin_amdgcn_mfma_f32_16x16x32_bf16(Ah, Bl, a, 0,0,0);
      a = __builtin_amdgcn_mfma_f32_16x16x32_bf16(Ah, Bh, a, 0,0,0);
      acc[ft] = a;
    }
  }
  #pragma unroll
  for(int r=0;r<4;r++){
    float e = epbs[quad*4 + r];
    #pragma unroll
    for(int ft=0;ft<3;ft++){
      int ftg = w2*3 + ft;
      Po[(ftg*16+lm)*17 + quad*4 + r] = (unsigned)f2h(acc[ft][r]*e);
    }
  }
  __syncthreads();
  unsigned int* vO32 = (unsigned int*)(Vg + (size_t)panel*96*64);
  #pragma unroll
  for(int wv=0; wv<6; wv++){
    int idx2 = wv*128 + tid;
    int g = idx2 >> 3, j = idx2 & 7;
    unsigned lo = Po[g*17 + 2*j] & 0xFFFFu;
    unsigned hi = Po[g*17 + 2*j + 1] & 0xFFFFu;
    vO32[g*32 + mt*8 + j] = lo | (hi<<16);
  }
}

// ---------------------------------------------------------------- k_attn
// R12 = R9 restored (best-measured config, total 176.6us). Wave-independent,
// bpermute-free key permutation, 32 q-rows/wave, S/PV software pipeline with
// 3-buffer LDS rotation, one barrier per body. V-from-global (R10/R11) was
// falsified twice: no latency cover at 2 waves/SIMD, and the allocator
// refuses to hold a 96-VGPR cross-barrier V dbuf (R11: VGPR stayed 108,
// loads sank to uses, dur 60.8 == R10's 60.4). LDS tile-t row-m holds
// actual key 32*(t&1)+8*(m>>2)+4*(t>>1)+(m&3) so S D-layout == PV A-layout.
#define LDSK  0
#define LDSKL 4096
#define LDSV  8192
#define BUFB  20480
__global__ __launch_bounds__(512)
__attribute__((amdgpu_waves_per_eu(2, 2)))
void k_attn(const unsigned short* __restrict__ Kgh,
            const unsigned short* __restrict__ Kgl,
            const unsigned short* __restrict__ Vg,
            float* __restrict__ ctx0){
  __shared__ __align__(16) unsigned char lds[3*BUFB];   // 61440 B
  int tid = threadIdx.x;
  int lane = tid & 63, w = tid >> 6;
  int lm = lane & 15, quad = lane >> 4;
  int blk = blockIdx.x;
  int b = blk & 3, kh = (blk>>2)&3, qb = blk >> 4;   // qb 0..15
  const unsigned short* KhB = Kgh + (size_t)b*NN*32;
  const unsigned short* KlB = Kgl + (size_t)b*NN*32;
  const unsigned short* VB  = Vg  + (size_t)b*64*96*64;
  float* ctx = ctx0 + (size_t)kh*CTXS + (size_t)b*NN*96;

  // Q fragments: two q-tiles per wave (B-operand: col=lm, k=quad*8+j)
  s16x8 qh[2], ql[2];
  #pragma unroll
  for(int q2=0;q2<2;q2++){
    size_t ro = (size_t)(qb*256 + w*32 + q2*16 + lm)*32 + (size_t)quad*8;
    qh[q2] = *(const s16x8*)(KhB + ro);
    ql[q2] = *(const s16x8*)(KlB + ro);
  }

  // loop-invariant LDS read offsets (swizzled)
  int kro = lm*64 + ((quad ^ ((lm>>1)&3))<<4);               // K tile row lm, col quad
  int vr0 = lm*128 + (((0*4+quad) ^ (lm&7))<<4);             // V chunk 0
  int vr1 = lm*128 + (((1*4+quad) ^ (lm&7))<<4);             // V chunk 1

  // staging assignment: granule g = tid + 512*rep (16B granules, 1280 total)
  // K/Kl source rows PERMUTED: LDS (t, rr) holds actual key
  //   kact = 32*(t&1) + 8*(rr>>2) + 4*(t>>1) + (rr&3)
  int dofs[3], sofs[3], sreg[3];
  #pragma unroll
  for(int rep=0;rep<3;rep++){
    int g = tid + 512*rep;
    if(g < 512){
      int gk = g & 255;
      int row = gk>>2, col = gk&3;          // row = t*16+rr in 0..63
      int t = row>>4, rr = row&15;
      int kact = 32*(t&1) + 8*(rr>>2) + 4*(t>>1) + (rr&3);
      sreg[rep] = (g<256)? 0 : 1;
      sofs[rep] = kact*64 + col*16;
      dofs[rep] = ((g<256)? LDSK : LDSKL) + row*64 + ((col ^ ((row>>1)&3))<<4);
    }
    else if(g < 1280){ int gv=g-512; sreg[rep]=2; sofs[rep]=gv*16;
      dofs[rep] = LDSV + (gv>>3)*128 + (((gv&7) ^ ((gv>>3)&7))<<4); }
    else { sreg[rep]=-1; sofs[rep]=0; dofs[rep]=0; }
  }

  f32x4 acc[2][6];
  #pragma unroll
  for(int q2=0;q2<2;q2++)
    #pragma unroll
    for(int ft=0;ft<6;ft++)
      #pragma unroll
      for(int i=0;i<4;i++) acc[q2][ft][i]=0.f;

  unsigned Wt[3][2][4][2];   // [bank = t%3][q2][kt][word] -- static idx only
  u32x4 stg0, stg1, stg2;

#define MFB(A,Bv,C) __builtin_amdgcn_mfma_f32_16x16x32_bf16(A,Bv,C,0,0,0)
#define MFH(A,Bv,C) __builtin_amdgcn_mfma_f32_16x16x32_f16(A,Bv,C,0,0,0)

#define STG_ISSUE(T) { \
  const char* kb_ = (const char*)(KhB + (size_t)(kh*16+(T))*2048); \
  const char* lb_ = (const char*)(KlB + (size_t)(kh*16+(T))*2048); \
  const char* vb_ = (const char*)(VB  + (size_t)(kh*16+(T))*6144); \
  { const char* sp_ = (sreg[0]==0)? kb_ : (sreg[0]==1)? lb_ : vb_; \
    stg0 = *(const u32x4*)(sp_ + sofs[0]); } \
  { const char* sp_ = (sreg[1]==0)? kb_ : (sreg[1]==1)? lb_ : vb_; \
    stg1 = *(const u32x4*)(sp_ + sofs[1]); } \
  if(sreg[2]>=0){ stg2 = *(const u32x4*)(vb_ + sofs[2]); } }

#define STG_WRITE(BN) { \
  *(u32x4*)&lds[(BN)*BUFB + dofs[0]] = stg0; \
  *(u32x4*)&lds[(BN)*BUFB + dofs[1]] = stg1; \
  if(sreg[2]>=0){ *(u32x4*)&lds[(BN)*BUFB + dofs[2]] = stg2; } }

// S-phase of panel in buf B -> Wt bank WB (no PV dependency this body)
#define SPH(B,WB) { \
  _Pragma("unroll") \
  for(int kt=0;kt<4;kt++){ \
    s16x8 kfh = *(const s16x8*)&lds[(B)*BUFB + LDSK  + kt*1024 + kro]; \
    s16x8 kfl = *(const s16x8*)&lds[(B)*BUFB + LDSKL + kt*1024 + kro]; \
    _Pragma("unroll") \
    for(int q2=0;q2<2;q2++){ \
      f32x4 s_ = {0.f,0.f,0.f,0.f}; \
      s_ = MFB(kfl, qh[q2], s_); \
      s_ = MFB(kfh, ql[q2], s_); \
      s_ = MFB(kfh, qh[q2], s_); \
      Wt[WB][q2][kt][0] = (unsigned)f2h(__expf(s_[0])) | ((unsigned)f2h(__expf(s_[1]))<<16); \
      Wt[WB][q2][kt][1] = (unsigned)f2h(__expf(s_[2])) | ((unsigned)f2h(__expf(s_[3]))<<16); \
    } \
  } }

// PV-phase: Wt bank WB (computed LAST body) x V in buf B
#define PVH(B,WB) { \
  _Pragma("unroll") \
  for(int c=0;c<2;c++){ \
    u32x4 paw0 = {Wt[WB][0][c][0], Wt[WB][0][c][1], Wt[WB][0][c+2][0], Wt[WB][0][c+2][1]}; \
    u32x4 paw1 = {Wt[WB][1][c][0], Wt[WB][1][c][1], Wt[WB][1][c+2][0], Wt[WB][1][c+2][1]}; \
    f16x8 PA0 = __builtin_bit_cast(f16x8, paw0); \
    f16x8 PA1 = __builtin_bit_cast(f16x8, paw1); \
    int vro_ = c ? vr1 : vr0; \
    _Pragma("unroll") \
    for(int ft=0;ft<6;ft++){ \
      f16x8 vf = *(const f16x8*)&lds[(B)*BUFB + LDSV + ft*2048 + vro_]; \
      acc[0][ft] = MFH(PA0, vf, acc[0][ft]); \
      acc[1][ft] = MFH(PA1, vf, acc[1][ft]); } \
  } }

  // ---- prologue: stage 0 -> B0; S(0) -> W0; stage 1 -> B1
  STG_ISSUE(0);
  STG_WRITE(0);
  __syncthreads();
  STG_ISSUE(1);
  SPH(0,0);
  STG_WRITE(1);
  __syncthreads();

  // ---- main: panels 1..15, 5 iterations x 3 bodies, one barrier/body.
  // body A (t=3it+1): S B1->W1, PV(t-1) B0/W0, write t+1 -> B2
  // body B (t=3it+2): S B2->W2, PV B1/W1, write -> B0
  // body C (t=3it+3): S B0->W0, PV B2/W2, write -> B1 (skip stage at it=4)
  #pragma unroll 1
  for(int it=0; it<5; it++){
    int tA = 3*it + 1;
    STG_ISSUE(tA+1);
    SPH(1,1);
    PVH(0,0);
    STG_WRITE(2);
    __syncthreads();
    STG_ISSUE(tA+2);
    SPH(2,2);
    PVH(1,1);
    STG_WRITE(0);
    __syncthreads();
    if(it<4){ STG_ISSUE(tA+3); }
    SPH(0,0);
    PVH(2,2);
    if(it<4){ STG_WRITE(1); }
    __syncthreads();
  }
  // ---- epilogue: PV(15): V in B0 (15%3==0), Wt bank 0
  PVH(0,0);

#undef MFB
#undef MFH
#undef STG_ISSUE
#undef STG_WRITE
#undef SPH
#undef PVH

  // ---- epilogue: ctx store (D-layout: col=lm per ft, row=quad*4+r)
  #pragma unroll
  for(int q2=0;q2<2;q2++){
    #pragma unroll
    for(int ft=0;ft<6;ft++){
      int col = ft*16 + lm;
      #pragma unroll
      for(int r=0;r<4;r++){
        int row = qb*256 + w*32 + q2*16 + quad*4 + r;
        ctx[(size_t)row*96 + col] = acc[q2][ft][r];
      }
    }
  }
}

// ---------------------------------------------------------------- k_out
// R7 config kept: 16 points/block, grid 2048, (256,4) -> no spills,
// 8 blocks/CU via 17.9KB LDS + 64-VGPR occupancy step.
__launch_bounds__(256, 4)
__global__ void k_out(const float* __restrict__ feat, const float* __restrict__ ctxA,
                      const float* __restrict__ w3jout, float* __restrict__ out){
  __shared__ float gbuf[16*45];
  __shared__ float fbuf[16*24];
  __shared__ float dls[4*64*13];
  __shared__ float inv[16];
  int tid = threadIdx.x;
  int typ = blockIdx.x & 1;
  int n0 = (blockIdx.x>>1)*16;
  int gc0 = typ*44;
  for(int i=tid;i<16*44;i+=256){
    int pt=i/44, c=i-pt*44;
    const float* base = ctxA + (size_t)(n0+pt)*96 + gc0 + c;
    gbuf[pt*45+c] = base[0]+base[CTXS]+base[2*CTXS]+base[3*CTXS];
  }
  for(int i=tid;i<16*22;i+=256){
    int pt=i/22, c=i-pt*22;
    fbuf[pt*24+c] = feat[(size_t)(n0+pt)*22+c];
  }
  if(tid<16){
    const float* bd = ctxA + (size_t)(n0+tid)*96 + 88;
    inv[tid] = 1.0f/(bd[0]+bd[CTXS]+bd[2*CTXS]+bd[3*CTXS]);
  }
  __syncthreads();
  int lane = tid&63, w = tid>>6;
  int pt = lane&15, sub = lane>>4;
  float fR[13], gR[13], d[13];
  {
    int FB = (w&2)?9:0;
    int fn = (w&2)?13:9;
    #pragma unroll 13
    for(int i=0;i<13;i++) fR[i] = (i<fn) ? fbuf[pt*24 + FB + i] : 0.f;
    int GBl = (w==0)?0:(w==1)?9:(w==2)?22:31;
    int jn = (w&1)?13:9;
    #pragma unroll 13
    for(int j=0;j<13;j++) gR[j] = (j<jn) ? gbuf[pt*45 + GBl + j] : 0.f;
  }
  #pragma unroll 13
  for(int k=0;k<13;k++) d[k]=0.f;

  // i-loop strided across sub: i = sub + 4*ii (ii count compile-time)
#define PATHR(ID,JD,KD,WO) \
  _Pragma("unroll") \
  for(int ii=0;ii<((ID)+3)/4;ii++){ int i=sub+4*ii; if(i<(ID)){ float fv=fR[i]; \
    _Pragma("unroll") \
    for(int j=0;j<(JD);j++){ float val=fv*gR[j]; \
      const float* wp = w3jout + (WO) + (i*(JD)+j)*(KD); \
      _Pragma("unroll") \
      for(int k=0;k<(KD);k++) d[k] = fmaf(val, wp[k], d[k]); } } }

  int pcase = typ*4 + w;
  switch(pcase){
    case 0: PATHR(9,9,9, 0)       break;
    case 1: PATHR(9,13,9, 729)    break;
    case 2: PATHR(13,9,9, 1782)   break;
    case 3: PATHR(13,13,9, 2835)  break;
    case 4: PATHR(9,9,13, 4356)   break;
    case 5: PATHR(9,13,13, 5409)  break;
    case 6: PATHR(13,9,13, 6930)  break;
    default:PATHR(13,13,13, 8451) break;
  }
#undef PATHR
  {
    float* dp = &dls[(w*64+lane)*13];
    #pragma unroll 13
    for(int k=0;k<13;k++) dp[k]=d[k];
  }
  __syncthreads();
  {
    int KD = typ?13:9;
    int kb = typ?9:0;
    int pt2 = tid&15, kc = tid>>4;   // kc 0..15
    if(kc < KD){
      float s = 0.f;
      #pragma unroll
      for(int ww=0;ww<4;ww++)
        #pragma unroll
        for(int ss=0;ss<4;ss++)
          s += dls[(ww*64 + ss*16 + pt2)*13 + kc];
      out[(size_t)(n0+pt2)*22 + kb + kc] = s*inv[pt2];
    }
  }
}

// ---------------------------------------------------------------- launch
extern "C" void kernel_launch(void* const* d_in, const int* in_sizes, int n_in,
                              void* d_out, int out_size, void* d_ws, size_t ws_size,
                              hipStream_t stream){
  (void)in_sizes; (void)n_in; (void)out_size; (void)ws_size;
  const float* feat =(const float*)d_in[0];
  const float* sh   =(const float*)d_in[1];
  const float* log_s=(const float*)d_in[2];
  const float* pos_w=(const float*)d_in[3];
  const float* pos_b=(const float*)d_in[4];
  const float* wli  =(const float*)d_in[5];
  const float* wval =(const float*)d_in[6];
  const float* wout =(const float*)d_in[7];
  const float* wlo  =(const float*)d_in[8];
  float* outp=(float*)d_out;
  float* wsf=(float*)d_ws;

  unsigned short* Kgh=(unsigned short*)((char*)d_ws + OFFB_KGH);
  unsigned short* Kgl=(unsigned short*)((char*)d_ws + OFFB_KGL);
  unsigned short* Vg =(unsigned short*)((char*)d_ws + OFFB_VG);
  unsigned short* WBH=(unsigned short*)((char*)d_ws + OFFB_WBH);
  unsigned short* WBL=(unsigned short*)((char*)d_ws + OFFB_WBL);

  hipLaunchKernelGGL(k_tab, dim3(14), dim3(512), 0, stream,
                     wsf+OFF_W3JVAL, wsf+OFF_W3JOUT);
  hipLaunchKernelGGL(k_weights, dim3(16), dim3(64), 0, stream,
                     wli, wval, wout, wlo, wsf+OFF_W3JVAL, WBH, WBL);
  hipLaunchKernelGGL(k_prep, dim3(1024), dim3(128), 0, stream,
                     feat, sh, log_s, pos_w, pos_b, WBH, WBL,
                     Kgh, Kgl, Vg);
  hipLaunchKernelGGL(k_attn, dim3(256), dim3(512), 0, stream,
                     Kgh, Kgl, Vg, wsf+OFF_CTX0);
  hipLaunchKernelGGL(k_out, dim3(2048), dim3(256), 0, stream,
                     feat, wsf+OFF_CTX0, wsf+OFF_W3JOUT, outp);
}